// Round 1
// baseline (25.397 us; speedup 1.0000x reference)
//
#include <hip/hip_runtime.h>

// CurvatureTotal: 3x3 stencil derivatives + fused curvature formula.
// z: (8,1,1024,1024) fp32 -> out same shape fp32.
// Cp*Ct simplifies: pow(og,1.5)*sqrt(og) = og^2, so
//   out = (numCp*numCt) / (denom_g * og)^2   -- no sqrt/pow needed.

namespace {

constexpr int W = 1024;
constexpr int H = 1024;
constexpr int NPLANES = 8;
constexpr float H_RES = 30.0f;
constexpr float EPS = 1e-12f;

__global__ __launch_bounds__(256) void curv_kernel(const float* __restrict__ z,
                                                   float* __restrict__ out) {
    const int x = blockIdx.x * 256 + threadIdx.x;
    const int y = blockIdx.y;
    const size_t plane = (size_t)blockIdx.z * (size_t)(W * H);
    const float* __restrict__ zp = z + plane;

    const bool wx0 = (x > 0), wx1 = (x < W - 1);
    const bool wy0 = (y > 0), wy1 = (y < H - 1);
    const int xm = wx0 ? x - 1 : 0;        // replicate-clamped
    const int xp = wx1 ? x + 1 : W - 1;
    const int ym = wy0 ? y - 1 : 0;
    const int yp = wy1 ? y + 1 : H - 1;

    const float* rowc = zp + (size_t)y * W;
    const float* rowm = zp + (size_t)ym * W;
    const float* rowp = zp + (size_t)yp * W;

    const float zc  = rowc[x];
    const float zw  = rowc[xm];
    const float ze  = rowc[xp];
    const float zn  = rowm[x];
    const float zs  = rowp[x];
    const float znw = rowm[xm];
    const float zne = rowm[xp];
    const float zsw = rowp[xm];
    const float zse = rowp[xp];

    // First derivatives: replicate padding (clamped taps).
    const float inv2h = 1.0f / (2.0f * H_RES);
    const float p = (ze - zw) * inv2h;
    const float q = (zs - zn) * inv2h;

    // Second derivatives: zero padding (mask out-of-bounds taps to 0).
    const float zwz  = wx0 ? zw : 0.0f;
    const float zez  = wx1 ? ze : 0.0f;
    const float znz  = wy0 ? zn : 0.0f;
    const float zsz  = wy1 ? zs : 0.0f;
    const float znwz = (wy0 && wx0) ? znw : 0.0f;
    const float znez = (wy0 && wx1) ? zne : 0.0f;
    const float zswz = (wy1 && wx0) ? zsw : 0.0f;
    const float zsez = (wy1 && wx1) ? zse : 0.0f;

    const float invh2  = 1.0f / (H_RES * H_RES);
    const float inv4h2 = 0.25f * invh2;
    const float r = (zez - 2.0f * zc + zwz) * invh2;   // d2/dx2
    const float t = (zsz - 2.0f * zc + znz) * invh2;   // d2/dy2
    const float s = (znwz - znez - zswz + zsez) * inv4h2; // d2/dxdy

    const float p2 = p * p, q2 = q * q, pq = p * q;
    const float denom_g = p2 + q2 + EPS;
    const float og      = 1.0f + p2 + q2 + EPS;

    const float numCp = p2 * r + 2.0f * pq * s + q2 * t;
    const float numCt = q2 * r - 2.0f * pq * s + p2 * t;

    // Cp*Ct = numCp*numCt / (denom_g^2 * og^1.5 * og^0.5)
    //       = numCp*numCt * (1/(denom_g*og))^2
    const float dn  = denom_g * og;
    const float rdn = __builtin_amdgcn_rcpf(dn);   // v_rcp_f32, ~1 ulp
    const float result = (numCp * numCt) * (rdn * rdn);

    __builtin_nontemporal_store(result, &out[plane + (size_t)y * W + x]);
}

}  // namespace

extern "C" void kernel_launch(void* const* d_in, const int* in_sizes, int n_in,
                              void* d_out, int out_size, void* d_ws, size_t ws_size,
                              hipStream_t stream) {
    const float* z = (const float*)d_in[0];
    float* out = (float*)d_out;
    dim3 grid(W / 256, H, NPLANES);
    dim3 block(256, 1, 1);
    curv_kernel<<<grid, block, 0, stream>>>(z, out);
}